// Round 1
// baseline (139.465 us; speedup 1.0000x reference)
//
#include <hip/hip_runtime.h>
#include <hip/hip_bf16.h>
#include <stdint.h>

#define NNODES 100000
#define DIN    256
#define DOUT   128
#define KNB    16

typedef __attribute__((ext_vector_type(8))) __bf16 bf16x8;
typedef __attribute__((ext_vector_type(4))) float  f32x4;

// ---------------------------------------------------------------------------
// Kernel 1: h = relu(feats @ W + b), stored as bf16 into workspace.
// Block = 256 threads (4 waves). Block tile = 128 rows x 128 cols, K = 256.
// Wave w owns cols [32w, 32w+32). B fragments (W) hoisted to registers once.
// A fragments loaded directly from global (f32 -> bf16 in regs). No LDS.
// MFMA 16x16x32 bf16; D layout: col = lane&15, row = (lane>>4)*4 + r.
// ---------------------------------------------------------------------------
__global__ __launch_bounds__(256, 2)
void gc_linear_relu(const float* __restrict__ feats,
                    const float* __restrict__ W,
                    const float* __restrict__ bias,
                    unsigned short* __restrict__ h)
{
    const int lane = threadIdx.x & 63;
    const int wave = threadIdx.x >> 6;      // 0..3
    const int brow = blockIdx.x * 128;
    const int wcol = wave * 32;

    const int fr = lane & 15;               // A-row / B-col / D-col within tile
    const int kb = lane >> 4;               // 0..3 (k-block)

    // ---- hoist B fragments: bfrag[ct][ks], W is [256][128] row-major ----
    bf16x8 bfrag[2][8];
    #pragma unroll
    for (int ct = 0; ct < 2; ++ct) {
        const int col = wcol + ct * 16 + fr;
        #pragma unroll
        for (int ks = 0; ks < 8; ++ks) {
            const int k0 = ks * 32 + kb * 8;
            bf16x8 f;
            #pragma unroll
            for (int j = 0; j < 8; ++j)
                f[j] = (__bf16)W[(k0 + j) * DOUT + col];
            bfrag[ct][ks] = f;
        }
    }

    f32x4 acc[8][2];
    #pragma unroll
    for (int rt = 0; rt < 8; ++rt)
        #pragma unroll
        for (int ct = 0; ct < 2; ++ct)
            acc[rt][ct] = (f32x4){0.f, 0.f, 0.f, 0.f};

    for (int rt = 0; rt < 8; ++rt) {
        int row = brow + rt * 16 + fr;
        if (row >= NNODES) row = NNODES - 1;       // clamp: safe load, store guarded
        const float* ap = feats + (size_t)row * DIN;
        #pragma unroll
        for (int ks = 0; ks < 8; ++ks) {
            const int k0 = ks * 32 + kb * 8;
            const float4 a0 = *reinterpret_cast<const float4*>(ap + k0);
            const float4 a1 = *reinterpret_cast<const float4*>(ap + k0 + 4);
            bf16x8 af;
            af[0] = (__bf16)a0.x; af[1] = (__bf16)a0.y;
            af[2] = (__bf16)a0.z; af[3] = (__bf16)a0.w;
            af[4] = (__bf16)a1.x; af[5] = (__bf16)a1.y;
            af[6] = (__bf16)a1.z; af[7] = (__bf16)a1.w;
            acc[rt][0] = __builtin_amdgcn_mfma_f32_16x16x32_bf16(af, bfrag[0][ks], acc[rt][0], 0, 0, 0);
            acc[rt][1] = __builtin_amdgcn_mfma_f32_16x16x32_bf16(af, bfrag[1][ks], acc[rt][1], 0, 0, 0);
        }
    }

    // ---- epilogue: +bias, relu, convert to bf16, store ----
    float bv[2];
    bv[0] = bias[wcol + fr];
    bv[1] = bias[wcol + 16 + fr];
    #pragma unroll
    for (int rt = 0; rt < 8; ++rt) {
        #pragma unroll
        for (int ct = 0; ct < 2; ++ct) {
            const int col = wcol + ct * 16 + fr;
            #pragma unroll
            for (int r = 0; r < 4; ++r) {
                const int grow = brow + rt * 16 + kb * 4 + r;
                if (grow < NNODES) {
                    float v = fmaxf(acc[rt][ct][r] + bv[ct], 0.f);
                    h[(size_t)grow * DOUT + col] =
                        __builtin_bit_cast(unsigned short, (__bf16)v);
                }
            }
        }
    }
}

// ---------------------------------------------------------------------------
// Kernel 2: out[i][:] = mean_k h[edge[i][k]][:]  (bf16 h -> f32 out)
// 4 nodes per 256-thread block; 64 lanes per node, 2 cols per lane (u32 load).
// ---------------------------------------------------------------------------
__global__ __launch_bounds__(256, 4)
void gc_gather_mean(const int* __restrict__ edge,
                    const unsigned short* __restrict__ h,
                    float* __restrict__ out)
{
    const int t  = threadIdx.x;
    const int ln = t >> 6;        // 0..3 local node
    const int c2 = t & 63;        // column-pair index
    const int node = blockIdx.x * 4 + ln;
    if (node >= NNODES) return;

    const int* ep = edge + node * KNB;
    float s0 = 0.f, s1 = 0.f;
    #pragma unroll
    for (int k = 0; k < KNB; ++k) {
        const int nb = ep[k];
        const uint32_t pk =
            *reinterpret_cast<const uint32_t*>(h + (size_t)nb * DOUT + c2 * 2);
        union { uint32_t u; float f; } lo, hi;
        lo.u = pk << 16;
        hi.u = pk & 0xFFFF0000u;
        s0 += lo.f;
        s1 += hi.f;
    }
    float2 o = make_float2(s0 * 0.0625f, s1 * 0.0625f);
    *reinterpret_cast<float2*>(out + (size_t)node * DOUT + c2 * 2) = o;
}

extern "C" void kernel_launch(void* const* d_in, const int* in_sizes, int n_in,
                              void* d_out, int out_size, void* d_ws, size_t ws_size,
                              hipStream_t stream)
{
    const float* feats = (const float*)d_in[0];
    const int*   edge  = (const int*)d_in[1];   // int32 on device (JAX default)
    const float* W     = (const float*)d_in[2];
    const float* bias  = (const float*)d_in[3];
    float* out = (float*)d_out;
    unsigned short* h = (unsigned short*)d_ws;  // bf16 h [NNODES][DOUT]

    if (ws_size < (size_t)NNODES * DOUT * sizeof(unsigned short)) return;

    const int gemm_blocks = (NNODES + 127) / 128;   // 782
    gc_linear_relu<<<gemm_blocks, 256, 0, stream>>>(feats, W, bias, h);

    const int gat_blocks = (NNODES + 3) / 4;        // 25000
    gc_gather_mean<<<gat_blocks, 256, 0, stream>>>(edge, h, out);
}